// Round 1
// baseline (7051.048 us; speedup 1.0000x reference)
//
#include <hip/hip_runtime.h>
#include <stdint.h>

#define B_    256
#define SE    49
#define TD    25
#define INDIM 69
#define RNN   2048
#define NZ    64
#define G3    6144   // 3*RNN

typedef __attribute__((ext_vector_type(8))) short short8_t;
typedef __attribute__((ext_vector_type(4))) float f32x4;

__device__ __forceinline__ float b2f(unsigned short u) {
  union { unsigned u; float f; } c; c.u = ((unsigned)u) << 16; return c.f;
}
__device__ __forceinline__ unsigned short f2b(float f) {
  union { float f; unsigned u; } c; c.f = f;
  unsigned u = c.u;
  return (unsigned short)((u + 0x7FFFu + ((u >> 16) & 1u)) >> 16);
}

// ---------------------------------------------------------------------------
// C[M,N] = A[M,K](bf16) @ W[N,K](bf16)^T + bias ;  M%128==0, N%128==0, K%64==0
// 256 threads = 4 waves in 2x2, each wave does 64x64 via 4x4 MFMA 16x16x32.
// ---------------------------------------------------------------------------
template<int OUT_BF16>
__global__ __launch_bounds__(256) void gemm_bt(
    const unsigned short* __restrict__ A,
    const unsigned short* __restrict__ W,
    const float* __restrict__ bias,
    float* __restrict__ Cf,
    unsigned short* __restrict__ Cb,
    int N, int K)
{
  constexpr int BM = 128, BN = 128, BK = 64, LDK = BK + 8;
  __shared__ unsigned short sA[BM * LDK];
  __shared__ unsigned short sW[BN * LDK];

  const int ntn  = N / BN;
  const int bm   = blockIdx.x / ntn;
  const int bn   = blockIdx.x % ntn;
  const int tid  = threadIdx.x;
  const int lane = tid & 63;
  const int wave = tid >> 6;
  const int wr   = wave >> 1;
  const int wc   = wave & 1;

  f32x4 acc[4][4];
#pragma unroll
  for (int i = 0; i < 4; ++i)
#pragma unroll
    for (int j = 0; j < 4; ++j) acc[i][j] = (f32x4)(0.0f);

  const int row0A = bm * BM;
  const int row0W = bn * BN;
  const int frow  = lane & 15;
  const int fkq   = (lane >> 4) * 8;

  for (int k0 = 0; k0 < K; k0 += BK) {
#pragma unroll
    for (int p = 0; p < 4; ++p) {
      int e = (p * 256 + tid) * 8;
      int r = e / BK, c = e % BK;
      *(short8_t*)&sA[r * LDK + c] =
          *(const short8_t*)&A[(size_t)(row0A + r) * K + k0 + c];
    }
#pragma unroll
    for (int p = 0; p < 4; ++p) {
      int e = (p * 256 + tid) * 8;
      int r = e / BK, c = e % BK;
      *(short8_t*)&sW[r * LDK + c] =
          *(const short8_t*)&W[(size_t)(row0W + r) * K + k0 + c];
    }
    __syncthreads();
#pragma unroll
    for (int kk = 0; kk < BK; kk += 32) {
      short8_t fa[4], fb[4];
#pragma unroll
      for (int m = 0; m < 4; ++m)
        fa[m] = *(const short8_t*)&sA[(wr * 64 + m * 16 + frow) * LDK + kk + fkq];
#pragma unroll
      for (int n = 0; n < 4; ++n)
        fb[n] = *(const short8_t*)&sW[(wc * 64 + n * 16 + frow) * LDK + kk + fkq];
#pragma unroll
      for (int m = 0; m < 4; ++m)
#pragma unroll
        for (int n = 0; n < 4; ++n)
          acc[m][n] = __builtin_amdgcn_mfma_f32_16x16x32_bf16(fa[m], fb[n], acc[m][n], 0, 0, 0);
    }
    __syncthreads();
  }

  const int crow = (lane >> 4) * 4;
  const int ccol = lane & 15;
#pragma unroll
  for (int n = 0; n < 4; ++n) {
    const int col = bn * BN + wc * 64 + n * 16 + ccol;
    const float bv = bias[col];
#pragma unroll
    for (int m = 0; m < 4; ++m) {
#pragma unroll
      for (int r = 0; r < 4; ++r) {
        const int rowi = bm * BM + wr * 64 + m * 16 + crow + r;
        const float v = acc[m][n][r] + bv;
        if (OUT_BF16) Cb[(size_t)rowi * N + col] = f2b(v);
        else          Cf[(size_t)rowi * N + col] = v;
      }
    }
  }
}

// fp32 -> bf16 with K padding (pad cols zeroed)
__global__ void cvt_pad(const float* __restrict__ src, unsigned short* __restrict__ dst,
                        int rows, int K, int Kp)
{
  const int total = rows * Kp;
  for (int i = blockIdx.x * blockDim.x + threadIdx.x; i < total;
       i += gridDim.x * blockDim.x) {
    int r = i / Kp, c = i % Kp;
    dst[i] = (c < K) ? f2b(src[(size_t)r * K + c]) : (unsigned short)0;
  }
}

// pairs[t*256+b][0:69]=enc[b][t]; [69:138]= t<48 ? enc[b][t+1] : dec[b][0]; pad->192
__global__ void build_pairs(const float* __restrict__ enc, const float* __restrict__ dec,
                            unsigned short* __restrict__ pairs)
{
  const int total = SE * B_ * 192;
  for (int i = blockIdx.x * blockDim.x + threadIdx.x; i < total;
       i += gridDim.x * blockDim.x) {
    int c  = i % 192;
    int rb = i / 192;
    int b  = rb & (B_ - 1);
    int t  = rb >> 8;
    float v = 0.0f;
    if (c < INDIM) {
      v = enc[((size_t)b * SE + t) * INDIM + c];
    } else if (c < 2 * INDIM) {
      int cc = c - INDIM;
      v = (t < SE - 1) ? enc[((size_t)b * SE + (t + 1)) * INDIM + cc]
                       : dec[(size_t)b * TD * INDIM + cc];
    }
    pairs[i] = f2b(v);
  }
}

__global__ void zero_h(float* __restrict__ h, unsigned short* __restrict__ hbf)
{
  int i = blockIdx.x * blockDim.x + threadIdx.x;
  if (i < B_ * RNN) { h[i] = 0.0f; hbf[i] = 0; }
}

// GRU gate fusion: r=sig(ir+hr); z=sig(iz+hz); n=tanh(in + r*hn); h'=(1-z)n+z*h
template<int GI_BF16>
__global__ void gru_gate(const void* __restrict__ gi_, const float* __restrict__ gh,
                         float* __restrict__ h, unsigned short* __restrict__ hbf)
{
  int i = blockIdx.x * blockDim.x + threadIdx.x;
  if (i >= B_ * RNN) return;
  int b = i >> 11, j = i & (RNN - 1);
  size_t base = (size_t)b * G3 + j;
  float ir, iz, in_;
  if (GI_BF16) {
    const unsigned short* gi = (const unsigned short*)gi_;
    ir = b2f(gi[base]); iz = b2f(gi[base + RNN]); in_ = b2f(gi[base + 2 * RNN]);
  } else {
    const float* gi = (const float*)gi_;
    ir = gi[base]; iz = gi[base + RNN]; in_ = gi[base + 2 * RNN];
  }
  float hr = gh[base], hz = gh[base + RNN], hn = gh[base + 2 * RNN];
  float r = 1.0f / (1.0f + expf(-(ir + hr)));
  float z = 1.0f / (1.0f + expf(-(iz + hz)));
  float n = tanhf(in_ + r * hn);
  float hv = (1.0f - z) * n + z * h[i];
  h[i] = hv;
  hbf[i] = f2b(hv);
}

// mu/sigma heads + reparam sample + build fc1 input (bf16, padded to 192)
__global__ __launch_bounds__(128) void latent_k(
    const float* __restrict__ state, const float* __restrict__ mu_w,
    const float* __restrict__ mu_b,  const float* __restrict__ sg_w,
    const float* __restrict__ sg_b,  const float* __restrict__ eps,
    const float* __restrict__ dec,   float* __restrict__ out_mu,
    float* __restrict__ out_lv,      unsigned short* __restrict__ fc1in)
{
  const int b = blockIdx.x;
  const int t = threadIdx.x;
  const float* w = (t < NZ) ? (mu_w + (size_t)t * RNN) : (sg_w + (size_t)(t - NZ) * RNN);
  const float* s = state + (size_t)b * RNN;
  float s0 = 0, s1 = 0, s2 = 0, s3 = 0;
  for (int k = 0; k < RNN; k += 4) {
    s0 += s[k] * w[k];     s1 += s[k + 1] * w[k + 1];
    s2 += s[k + 2] * w[k + 2]; s3 += s[k + 3] * w[k + 3];
  }
  float dotv = (s0 + s1) + (s2 + s3);
  dotv += (t < NZ) ? mu_b[t] : sg_b[t - NZ];
  __shared__ float smu[NZ], slv[NZ];
  if (t < NZ) { out_mu[b * NZ + t] = dotv; smu[t] = dotv; }
  else        { out_lv[b * NZ + (t - NZ)] = dotv; slv[t - NZ] = dotv; }
  __syncthreads();
  for (int c = t; c < 192; c += 128) {
    float v = 0.0f;
    if (c < NZ)              v = smu[c] + eps[b * NZ + c] * expf(0.5f * slv[c]);
    else if (c < NZ + INDIM) v = dec[(size_t)b * TD * INDIM + (c - NZ)];
    fc1in[b * 192 + c] = f2b(v);
  }
}

// decoder init: inp = dec0 (fp32 + padded bf16); hbf = bf16(h)
__global__ void dec_init(const float* __restrict__ dec, const float* __restrict__ h,
                         float* __restrict__ inp, unsigned short* __restrict__ inpbf,
                         unsigned short* __restrict__ hbf)
{
  int i = blockIdx.x * blockDim.x + threadIdx.x;
  if (i < B_ * 128) {
    int b = i >> 7, c = i & 127;
    float v = (c < INDIM) ? dec[(size_t)b * TD * INDIM + c] : 0.0f;
    inpbf[i] = f2b(v);
    if (c < INDIM) inp[b * INDIM + c] = v;
  }
  if (i < B_ * RNN) hbf[i] = f2b(h[i]);
}

// out = inp + h @ fc2_w^T + fc2_b ; writes d_out[:,t,:], updates inp (fp32+bf16)
__global__ __launch_bounds__(256) void fc2_res(
    const float* __restrict__ h, const float* __restrict__ w,
    const float* __restrict__ bias, float* __restrict__ inp,
    unsigned short* __restrict__ inpbf, float* __restrict__ out, int t)
{
  int i = blockIdx.x * blockDim.x + threadIdx.x;
  if (i >= B_ * INDIM) return;
  int b = i / INDIM, o = i % INDIM;
  const float* hv = h + (size_t)b * RNN;
  const float* wv = w + (size_t)o * RNN;
  float s0 = 0, s1 = 0, s2 = 0, s3 = 0;
#pragma unroll 8
  for (int k = 0; k < RNN; k += 4) {
    s0 += hv[k] * wv[k];         s1 += hv[k + 1] * wv[k + 1];
    s2 += hv[k + 2] * wv[k + 2]; s3 += hv[k + 3] * wv[k + 3];
  }
  float v = inp[i] + ((s0 + s1) + (s2 + s3)) + bias[o];
  out[((size_t)b * TD + t) * INDIM + o] = v;
  inp[i] = v;
  inpbf[b * 128 + o] = f2b(v);
}

extern "C" void kernel_launch(void* const* d_in, const int* in_sizes, int n_in,
                              void* d_out, int out_size, void* d_ws, size_t ws_size,
                              hipStream_t stream)
{
  const float* enc    = (const float*)d_in[0];
  const float* dec    = (const float*)d_in[1];
  const float* eps    = (const float*)d_in[2];
  const float* fc0_w  = (const float*)d_in[3];
  const float* fc0_b  = (const float*)d_in[4];
  const float* fc1_w  = (const float*)d_in[5];
  const float* fc1_b  = (const float*)d_in[6];
  const float* fc2_w  = (const float*)d_in[7];
  const float* fc2_b  = (const float*)d_in[8];
  const float* mu_w   = (const float*)d_in[9];
  const float* mu_b   = (const float*)d_in[10];
  const float* sg_w   = (const float*)d_in[11];
  const float* sg_b   = (const float*)d_in[12];
  const float* c1_wih = (const float*)d_in[13];
  const float* c1_whh = (const float*)d_in[14];
  const float* c1_bih = (const float*)d_in[15];
  const float* c1_bhh = (const float*)d_in[16];
  const float* c2_wih = (const float*)d_in[17];
  const float* c2_whh = (const float*)d_in[18];
  const float* c2_bih = (const float*)d_in[19];
  const float* c2_bhh = (const float*)d_in[20];

  float* out_outputs = (float*)d_out;                      // [256,25,69]
  float* out_mu      = out_outputs + (size_t)B_ * TD * INDIM;
  float* out_lv      = out_mu + (size_t)B_ * NZ;

  char* ws = (char*)d_ws;
  size_t off = 0;
  auto alloc = [&](size_t bytes) -> void* {
    void* p = ws + off; off += (bytes + 255) & ~(size_t)255; return p;
  };

  unsigned short* w_c1wih = (unsigned short*)alloc((size_t)G3 * RNN * 2);
  unsigned short* w_c1whh = (unsigned short*)alloc((size_t)G3 * RNN * 2);
  unsigned short* w_c2whh = (unsigned short*)alloc((size_t)G3 * RNN * 2);
  unsigned short* w_c2wih = (unsigned short*)alloc((size_t)G3 * 128 * 2);
  unsigned short* w_fc0   = (unsigned short*)alloc((size_t)RNN * 192 * 2);
  unsigned short* w_fc1   = (unsigned short*)alloc((size_t)RNN * 192 * 2);
  unsigned short* pairs   = (unsigned short*)alloc((size_t)SE * B_ * 192 * 2);
  unsigned short* xbf     = (unsigned short*)alloc((size_t)SE * B_ * RNN * 2);
  float*          hf      = (float*)alloc((size_t)B_ * RNN * 4);
  unsigned short* hbf     = (unsigned short*)alloc((size_t)B_ * RNN * 2);
  float*          ghb     = (float*)alloc((size_t)B_ * G3 * 4);
  float*          gidec   = (float*)alloc((size_t)B_ * G3 * 4);
  unsigned short* fc1in   = (unsigned short*)alloc((size_t)B_ * 192 * 2);
  float*          inp     = (float*)alloc((size_t)B_ * INDIM * 4);
  unsigned short* inpbf   = (unsigned short*)alloc((size_t)B_ * 128 * 2);

  unsigned short* giall = nullptr;
  if (off + (size_t)SE * B_ * G3 * 2 <= ws_size)
    giall = (unsigned short*)alloc((size_t)SE * B_ * G3 * 2);

  // ---- weight conversion (every call; no caching allowed) ----
  cvt_pad<<<2048, 256, 0, stream>>>(c1_wih, w_c1wih, G3, RNN, RNN);
  cvt_pad<<<2048, 256, 0, stream>>>(c1_whh, w_c1whh, G3, RNN, RNN);
  cvt_pad<<<2048, 256, 0, stream>>>(c2_whh, w_c2whh, G3, RNN, RNN);
  cvt_pad<<<512, 256, 0, stream>>>(c2_wih, w_c2wih, G3, INDIM, 128);
  cvt_pad<<<512, 256, 0, stream>>>(fc0_w, w_fc0, RNN, 2 * INDIM, 192);
  cvt_pad<<<512, 256, 0, stream>>>(fc1_w, w_fc1, RNN, NZ + INDIM, 192);

  build_pairs<<<2048, 256, 0, stream>>>(enc, dec, pairs);
  zero_h<<<(B_ * RNN + 255) / 256, 256, 0, stream>>>(hf, hbf);

  // fc0: x = pairs @ fc0^T + b   [12544 x 2048], K=192, bf16 out
  gemm_bt<1><<<(SE * B_ / 128) * (RNN / 128), 256, 0, stream>>>(
      pairs, w_fc0, fc0_b, nullptr, xbf, RNN, 192);

  // all encoder input gates in one big GEMM: [12544 x 6144], K=2048
  if (giall)
    gemm_bt<1><<<(SE * B_ / 128) * (G3 / 128), 256, 0, stream>>>(
        xbf, w_c1wih, c1_bih, nullptr, giall, G3, RNN);

  // ---- encoder recurrence ----
  for (int t = 0; t < SE; ++t) {
    if (!giall)
      gemm_bt<0><<<(B_ / 128) * (G3 / 128), 256, 0, stream>>>(
          xbf + (size_t)t * B_ * RNN, w_c1wih, c1_bih, gidec, nullptr, G3, RNN);
    gemm_bt<0><<<(B_ / 128) * (G3 / 128), 256, 0, stream>>>(
        hbf, w_c1whh, c1_bhh, ghb, nullptr, G3, RNN);
    if (giall)
      gru_gate<1><<<(B_ * RNN + 255) / 256, 256, 0, stream>>>(
          giall + (size_t)t * B_ * G3, ghb, hf, hbf);
    else
      gru_gate<0><<<(B_ * RNN + 255) / 256, 256, 0, stream>>>(gidec, ghb, hf, hbf);
  }

  // ---- latent + fc1 ----
  latent_k<<<B_, 128, 0, stream>>>(hf, mu_w, mu_b, sg_w, sg_b, eps, dec,
                                   out_mu, out_lv, fc1in);
  gemm_bt<0><<<(B_ / 128) * (RNN / 128), 256, 0, stream>>>(
      fc1in, w_fc1, fc1_b, hf, nullptr, RNN, 192);
  dec_init<<<(B_ * RNN + 255) / 256, 256, 0, stream>>>(dec, hf, inp, inpbf, hbf);

  // ---- decoder recurrence ----
  for (int t = 0; t < TD; ++t) {
    gemm_bt<0><<<(B_ / 128) * (G3 / 128), 256, 0, stream>>>(
        inpbf, w_c2wih, c2_bih, gidec, nullptr, G3, 128);
    gemm_bt<0><<<(B_ / 128) * (G3 / 128), 256, 0, stream>>>(
        hbf, w_c2whh, c2_bhh, ghb, nullptr, G3, RNN);
    gru_gate<0><<<(B_ * RNN + 255) / 256, 256, 0, stream>>>(gidec, ghb, hf, hbf);
    fc2_res<<<(B_ * INDIM + 255) / 256, 256, 0, stream>>>(
        hf, fc2_w, fc2_b, inp, inpbf, out_outputs, t);
  }
}

// Round 3
// 2269.539 us; speedup vs baseline: 3.1068x; 3.1068x over previous
//
#include <hip/hip_runtime.h>
#include <stdint.h>

#define B_    256
#define SE    49
#define TD    25
#define INDIM 69
#define RNN   2048
#define NZ    64
#define G3    6144

typedef __attribute__((ext_vector_type(8))) short short8_t;
typedef __attribute__((ext_vector_type(4))) float f32x4;
typedef unsigned short u16;

__device__ __forceinline__ float b2f(u16 u) {
  union { unsigned u; float f; } c; c.u = ((unsigned)u) << 16; return c.f;
}
__device__ __forceinline__ u16 f2b(float f) {
  union { float f; unsigned u; } c; c.f = f;
  unsigned u = c.u;
  return (u16)((u + 0x7FFFu + ((u >> 16) & 1u)) >> 16);
}
__device__ __forceinline__ float sigm(float x) { return 1.f / (1.f + __expf(-x)); }

// reordered row R (gate-grouped per 32-col block) -> original row of [3*RNN]
__device__ __forceinline__ int rmap(int R) {
  int j = (R / 96) * 32 + (R & 31);
  int g = (R % 96) >> 5;
  return g * RNN + j;
}

// ===========================================================================
// prep kernels
// ===========================================================================
__global__ void k_reorder(const float* __restrict__ src, u16* __restrict__ dst, int K, int Kp) {
  int total = G3 * Kp;
  for (int i = blockIdx.x * blockDim.x + threadIdx.x; i < total; i += gridDim.x * blockDim.x) {
    int R = i / Kp, c = i % Kp;
    dst[i] = (c < K) ? f2b(src[(size_t)rmap(R) * K + c]) : (u16)0;
  }
}

__global__ void k_fc0T(const float* __restrict__ fc0w, u16* __restrict__ dst) {
  int total = 256 * RNN;
  for (int i = blockIdx.x * blockDim.x + threadIdx.x; i < total; i += gridDim.x * blockDim.x) {
    int r = i >> 11, k = i & (RNN - 1);
    dst[i] = (r < 2 * INDIM) ? f2b(fc0w[(size_t)k * (2 * INDIM) + r]) : (u16)0;
  }
}

__global__ void k_fc2T(const float* __restrict__ fc2w, u16* __restrict__ dst) {
  int total = 96 * RNN;
  for (int i = blockIdx.x * blockDim.x + threadIdx.x; i < total; i += gridDim.x * blockDim.x) {
    int r = i >> 11, k = i & (RNN - 1);
    dst[i] = (r < INDIM) ? f2b(fc2w[(size_t)r * RNN + k]) : (u16)0;
  }
}

__global__ void k_pairs(const float* __restrict__ enc, const float* __restrict__ dec,
                        u16* __restrict__ pairs) {
  int total = SE * B_ * 256;
  for (int i = blockIdx.x * blockDim.x + threadIdx.x; i < total; i += gridDim.x * blockDim.x) {
    int c = i & 255, rb = i >> 8;
    int b = rb & 255, t = rb >> 8;
    float v = 0.f;
    if (c < INDIM) v = enc[((size_t)b * SE + t) * INDIM + c];
    else if (c < 2 * INDIM) {
      int cc = c - INDIM;
      v = (t < SE - 1) ? enc[((size_t)b * SE + t + 1) * INDIM + cc]
                       : dec[(size_t)b * TD * INDIM + cc];
    }
    pairs[i] = f2b(v);
  }
}

__global__ void k_bias(const float* __restrict__ c1wih, const float* __restrict__ fc0b,
                       const float* __restrict__ c1bih, const float* __restrict__ c1bhh,
                       const float* __restrict__ c2wih, const float* __restrict__ fc2b,
                       const float* __restrict__ c2bih, const float* __restrict__ c2bhh,
                       float* __restrict__ ebi, float* __restrict__ ebh,
                       float* __restrict__ dbi0, float* __restrict__ dbi1, float* __restrict__ dbh) {
  int R = blockIdx.x;
  int orig = rmap(R);
  float s = 0.f;
  for (int k = threadIdx.x; k < RNN; k += 256) s += c1wih[(size_t)orig * RNN + k] * fc0b[k];
  __shared__ float red[256];
  red[threadIdx.x] = s; __syncthreads();
  for (int st = 128; st > 0; st >>= 1) {
    if (threadIdx.x < st) red[threadIdx.x] += red[threadIdx.x + st];
    __syncthreads();
  }
  if (threadIdx.x == 0) {
    float k3 = 0.f;
    for (int o = 0; o < INDIM; ++o) k3 += c2wih[(size_t)orig * INDIM + o] * fc2b[o];
    ebi[R] = red[0] + c1bih[orig];
    ebh[R] = c1bhh[orig];
    float d0 = c2bih[orig];
    dbi0[R] = d0;
    dbi1[R] = d0 + k3;
    dbh[R] = c2bhh[orig];
  }
}

// zero h slot0 + fbuf[3]
__global__ void k_init(float* __restrict__ hf, u16* __restrict__ hbf, float* __restrict__ fbuf) {
  int i = blockIdx.x * blockDim.x + threadIdx.x;
  if (i < B_ * RNN) { hf[i] = 0.f; hbf[i] = 0; }
  if (i < 3 * B_ * 96) fbuf[i] = 0.f;
}

// ---------------------------------------------------------------------------
// bulk GEMM (round-1 proven structure): C[M,N] = A[M,K]bf16 @ W[N,K]bf16^T
// used once: Wenc = wih1_r @ fc0T^T   (M=6144, N=256, K=2048)
// ---------------------------------------------------------------------------
__global__ __launch_bounds__(256) void gemm_bt(
    const u16* __restrict__ A, const u16* __restrict__ W,
    u16* __restrict__ Cb, int N, int K)
{
  constexpr int BM = 128, BN = 128, BK = 64, LDK = BK + 8;
  __shared__ u16 sA[BM * LDK];
  __shared__ u16 sW[BN * LDK];
  const int ntn = N / BN;
  const int bm = blockIdx.x / ntn, bn = blockIdx.x % ntn;
  const int tid = threadIdx.x, lane = tid & 63, wave = tid >> 6;
  const int wr = wave >> 1, wc = wave & 1;
  f32x4 acc[4][4];
#pragma unroll
  for (int i = 0; i < 4; ++i)
#pragma unroll
    for (int j = 0; j < 4; ++j) acc[i][j] = (f32x4)(0.f);
  const int frow = lane & 15, fkq = (lane >> 4) * 8;
  for (int k0 = 0; k0 < K; k0 += BK) {
#pragma unroll
    for (int p = 0; p < 4; ++p) {
      int e = (p * 256 + tid) * 8, r = e / BK, c = e % BK;
      *(short8_t*)&sA[r * LDK + c] = *(const short8_t*)&A[(size_t)(bm * BM + r) * K + k0 + c];
    }
#pragma unroll
    for (int p = 0; p < 4; ++p) {
      int e = (p * 256 + tid) * 8, r = e / BK, c = e % BK;
      *(short8_t*)&sW[r * LDK + c] = *(const short8_t*)&W[(size_t)(bn * BN + r) * K + k0 + c];
    }
    __syncthreads();
#pragma unroll
    for (int kk = 0; kk < BK; kk += 32) {
      short8_t fa[4], fb[4];
#pragma unroll
      for (int m = 0; m < 4; ++m) fa[m] = *(const short8_t*)&sA[(wr * 64 + m * 16 + frow) * LDK + kk + fkq];
#pragma unroll
      for (int n = 0; n < 4; ++n) fb[n] = *(const short8_t*)&sW[(wc * 64 + n * 16 + frow) * LDK + kk + fkq];
#pragma unroll
      for (int m = 0; m < 4; ++m)
#pragma unroll
        for (int n = 0; n < 4; ++n)
          acc[m][n] = __builtin_amdgcn_mfma_f32_16x16x32_bf16(fa[m], fb[n], acc[m][n], 0, 0, 0);
    }
    __syncthreads();
  }
  const int crow = (lane >> 4) * 4, ccol = lane & 15;
#pragma unroll
  for (int n = 0; n < 4; ++n) {
    int col = bn * BN + wc * 64 + n * 16 + ccol;
#pragma unroll
    for (int m = 0; m < 4; ++m)
#pragma unroll
      for (int r = 0; r < 4; ++r) {
        int rowi = bm * BM + wr * 64 + m * 16 + crow + r;
        Cb[(size_t)rowi * N + col] = f2b(acc[m][n][r]);
      }
  }
}

// ===========================================================================
// step kernels (grid 256 = 4 m-tiles x 64 n-tiles, block 256 = 4 waves)
// LDS 40960B: sA @0 (64x256B), sW @16384 (96x256B); reduce S @0 (32KB) aliased
// ===========================================================================
struct Args {
  const u16 *pairs, *Wenc, *whh1, *whh2, *wih2, *fc2T;
  const float *ebi, *ebh, *dbi0, *dbi1, *dbh;
  const float *eps, *dec, *mu_w, *mu_b, *sg_w, *sg_b, *fc1_w, *fc1_b, *fc2_b;
  float* hf;    // [2][256][2048]
  u16*   hbf;   // [2][256][2048]
  float* fbuf;  // [3][256][96]
  float* inp;   // [2][256][69]
  u16*   inpbf; // [2][256][128]
  float *out, *out_mu, *out_lv;
};

__device__ __forceinline__ void stage_AW(short8_t (&ra)[4], short8_t (&rw)[6],
    const u16* A, int sAe, int rowA0, const u16* W, int sWe, int rowW0, int k0, int tid) {
#pragma unroll
  for (int p = 0; p < 4; ++p) {
    int s = tid + p * 256, r = s >> 4, c = s & 15;
    ra[p] = *(const short8_t*)&A[(size_t)(rowA0 + r) * sAe + k0 + c * 8];
  }
#pragma unroll
  for (int p = 0; p < 6; ++p) {
    int s = tid + p * 256, r = s >> 4, c = s & 15;
    rw[p] = *(const short8_t*)&W[(size_t)(rowW0 + r) * sWe + k0 + c * 8];
  }
}

__device__ __forceinline__ void write_AW(char* sAb, char* sWb,
    short8_t (&ra)[4], short8_t (&rw)[6], int tid) {
#pragma unroll
  for (int p = 0; p < 4; ++p) {
    int s = tid + p * 256, r = s >> 4, c = s & 15;
    *(short8_t*)&sAb[r * 256 + ((c * 16) ^ ((r & 7) << 4))] = ra[p];
  }
#pragma unroll
  for (int p = 0; p < 6; ++p) {
    int s = tid + p * 256, r = s >> 4, c = s & 15;
    *(short8_t*)&sWb[r * 256 + ((c * 16) ^ ((r & 7) << 4))] = rw[p];
  }
}

__device__ __forceinline__ void write_A(char* sAb, short8_t (&ra)[4], int tid) {
#pragma unroll
  for (int p = 0; p < 4; ++p) {
    int s = tid + p * 256, r = s >> 4, c = s & 15;
    *(short8_t*)&sAb[r * 256 + ((c * 16) ^ ((r & 7) << 4))] = ra[p];
  }
}

__device__ __forceinline__ void compute_iter(const char* sAb, const char* sWb,
    f32x4 (&acc)[4][6], f32x4 (&acc2)[4][2], int lane, int wid, int gh) {
  const int kb = wid * 64 + ((lane >> 4) << 4);
  short8_t fa[4], fb[6];
#pragma unroll
  for (int m = 0; m < 4; ++m) {
    int r = m * 16 + (lane & 15);
    fa[m] = *(const short8_t*)&sAb[r * 256 + (kb ^ ((r & 7) << 4))];
  }
#pragma unroll
  for (int n = 0; n < 6; ++n) {
    int r = n * 16 + (lane & 15);
    fb[n] = *(const short8_t*)&sWb[r * 256 + (kb ^ ((r & 7) << 4))];
  }
#pragma unroll
  for (int m = 0; m < 4; ++m) {
#pragma unroll
    for (int n = 0; n < 4; ++n)
      acc[m][n] = __builtin_amdgcn_mfma_f32_16x16x32_bf16(fa[m], fb[n], acc[m][n], 0, 0, 0);
    if (gh) {
      acc2[m][0] = __builtin_amdgcn_mfma_f32_16x16x32_bf16(fa[m], fb[4], acc2[m][0], 0, 0, 0);
      acc2[m][1] = __builtin_amdgcn_mfma_f32_16x16x32_bf16(fa[m], fb[5], acc2[m][1], 0, 0, 0);
    } else {
      acc[m][4] = __builtin_amdgcn_mfma_f32_16x16x32_bf16(fa[m], fb[4], acc[m][4], 0, 0, 0);
      acc[m][5] = __builtin_amdgcn_mfma_f32_16x16x32_bf16(fa[m], fb[5], acc[m][5], 0, 0, 0);
    }
  }
}

// 4-wave k-split reduce (single 32KB buffer, 7 barriers) + fused GRU gate
__device__ void reduce_gate(f32x4 (&acc)[4][6], f32x4 (&acc2)[4][2], char* smem,
    int tid, int bm, int bn, const float* bi, const float* bh,
    const float* hfold, float* hfnew, u16* hbnew) {
  const int lane = tid & 63, wid = tid >> 6;
  float* S = (float*)smem;
  auto wrp = [&]() {
#pragma unroll
    for (int m = 0; m < 4; ++m) {
#pragma unroll
      for (int n = 0; n < 6; ++n)
#pragma unroll
        for (int q = 0; q < 4; ++q)
          S[(m * 16 + ((lane >> 4) << 2) + q) * 128 + n * 16 + (lane & 15)] = acc[m][n][q];
#pragma unroll
      for (int n2 = 0; n2 < 2; ++n2)
#pragma unroll
        for (int q = 0; q < 4; ++q)
          S[(m * 16 + ((lane >> 4) << 2) + q) * 128 + 96 + n2 * 16 + (lane & 15)] = acc2[m][n2][q];
    }
  };
  auto addp = [&]() {
#pragma unroll
    for (int m = 0; m < 4; ++m) {
#pragma unroll
      for (int n = 0; n < 6; ++n)
#pragma unroll
        for (int q = 0; q < 4; ++q)
          acc[m][n][q] += S[(m * 16 + ((lane >> 4) << 2) + q) * 128 + n * 16 + (lane & 15)];
#pragma unroll
      for (int n2 = 0; n2 < 2; ++n2)
#pragma unroll
        for (int q = 0; q < 4; ++q)
          acc2[m][n2][q] += S[(m * 16 + ((lane >> 4) << 2) + q) * 128 + 96 + n2 * 16 + (lane & 15)];
    }
  };
  __syncthreads();
  if (wid == 1) wrp();
  __syncthreads();
  if (wid == 0) addp();
  __syncthreads();
  if (wid == 3) wrp();
  __syncthreads();
  if (wid == 2) addp();
  __syncthreads();
  if (wid == 2) wrp();
  __syncthreads();
  if (wid == 0) { addp(); wrp(); }
  __syncthreads();
  const int row = tid >> 2, grp = tid & 3;
  const int b = bm * 64 + row;
#pragma unroll
  for (int cc = 0; cc < 8; ++cc) {
    int c = grp * 8 + ((cc + row) & 7);   // bank-rotated read order
    float sr = S[row * 128 + c]      + bi[bn * 96 + c]      + bh[bn * 96 + c];
    float sz = S[row * 128 + 32 + c] + bi[bn * 96 + 32 + c] + bh[bn * 96 + 32 + c];
    float ni = S[row * 128 + 64 + c] + bi[bn * 96 + 64 + c];
    float hn = S[row * 128 + 96 + c] + bh[bn * 96 + 64 + c];
    float r = sigm(sr), z = sigm(sz);
    float nn = 2.f * sigm(2.f * (ni + r * hn)) - 1.f;
    int j = bn * 32 + c;
    float ho = hfold[(size_t)b * RNN + j];
    float hv = (1.f - z) * nn + z * ho;
    hfnew[(size_t)b * RNN + j] = hv;
    hbnew[(size_t)b * RNN + j] = f2b(hv);
  }
}

// distributed fc2 mini-GEMM: fdst[rows bm*64..][96] += hsrc[rows][k=bn*32..] @ fc2T^T
__device__ void fc2_mini(const Args& a, const u16* hsrc, float* fdst,
                         int bm, int bn, int tid, char* smem) {
  __syncthreads();
  const int lane = tid & 63, wid = tid >> 6, wr = wid >> 1, wc = wid & 1;
  { int r = tid >> 2, c16 = tid & 3;
    *(short8_t*)&smem[r * 80 + c16 * 16] =
        *(const short8_t*)&hsrc[(size_t)(bm * 64 + r) * RNN + bn * 32 + c16 * 8]; }
#pragma unroll
  for (int p = 0; p < 2; ++p) {
    int s = tid + p * 256;
    if (s < 384) {
      int r = s >> 2, c16 = s & 3;
      *(short8_t*)&smem[5120 + r * 80 + c16 * 16] =
          *(const short8_t*)&a.fc2T[(size_t)r * RNN + bn * 32 + c16 * 8];
    }
  }
  __syncthreads();
  short8_t fa[2], fb[3];
  f32x4 accf[2][3];
#pragma unroll
  for (int m = 0; m < 2; ++m)
#pragma unroll
    for (int n = 0; n < 3; ++n) accf[m][n] = (f32x4)(0.f);
#pragma unroll
  for (int m = 0; m < 2; ++m) {
    int r = wr * 32 + m * 16 + (lane & 15);
    fa[m] = *(const short8_t*)&smem[r * 80 + ((lane >> 4) << 4)];
  }
#pragma unroll
  for (int n = 0; n < 3; ++n) {
    int r = wc * 48 + n * 16 + (lane & 15);
    fb[n] = *(const short8_t*)&smem[5120 + r * 80 + ((lane >> 4) << 4)];
  }
#pragma unroll
  for (int m = 0; m < 2; ++m)
#pragma unroll
    for (int n = 0; n < 3; ++n)
      accf[m][n] = __builtin_amdgcn_mfma_f32_16x16x32_bf16(fa[m], fb[n], accf[m][n], 0, 0, 0);
#pragma unroll
  for (int m = 0; m < 2; ++m)
#pragma unroll
    for (int n = 0; n < 3; ++n)
#pragma unroll
      for (int q = 0; q < 4; ++q) {
        int row = bm * 64 + wr * 32 + m * 16 + ((lane >> 4) << 2) + q;
        int col = wc * 48 + n * 16 + (lane & 15);
        atomicAdd(&fdst[row * 96 + col], accf[m][n][q]);
      }
}

// ---- encoder step: h[t&1] -> h[(t&1)^1] --------------------------------
__global__ __launch_bounds__(256, 1) void k_enc(Args a, int t) {
  __shared__ char smem[40960];
  const int tid = threadIdx.x, lane = tid & 63, wid = tid >> 6;
  const int bm = blockIdx.x >> 6, bn = blockIdx.x & 63;
  const int rowA0 = bm * 64, rowW0 = bn * 96;
  const int pin = t & 1, pout = pin ^ 1;
  const u16* hin = a.hbf + (size_t)pin * B_ * RNN;
  const float* hfold = a.hf + (size_t)pin * B_ * RNN;
  float* hfnew = a.hf + (size_t)pout * B_ * RNN;
  u16* hbnew = a.hbf + (size_t)pout * B_ * RNN;

  f32x4 acc[4][6], acc2[4][2];
#pragma unroll
  for (int m = 0; m < 4; ++m) {
#pragma unroll
    for (int n = 0; n < 6; ++n) acc[m][n] = (f32x4)(0.f);
    acc2[m][0] = (f32x4)(0.f); acc2[m][1] = (f32x4)(0.f);
  }

  const u16* P = a.pairs + (size_t)t * B_ * 256;
  short8_t ra[4], rw[6], ra2[4], rw2[6];
  // gi iter 0
  stage_AW(ra, rw, P, 256, rowA0, a.Wenc, 256, rowW0, 0, tid);
  __syncthreads();
  write_AW(smem, smem + 16384, ra, rw, tid);
  stage_AW(ra2, rw2, P, 256, rowA0, a.Wenc, 256, rowW0, 128, tid);
  __syncthreads();
  compute_iter(smem, smem + 16384, acc, acc2, lane, wid, 0);
  // gi iter 1 (+ prefetch gh iter 0)
  __syncthreads();
  write_AW(smem, smem + 16384, ra2, rw2, tid);
  stage_AW(ra, rw, hin, RNN, rowA0, a.whh1, RNN, rowW0, 0, tid);
  __syncthreads();
  compute_iter(smem, smem + 16384, acc, acc2, lane, wid, 0);
  // gh loop
  for (int ii = 0; ii < 16; ++ii) {
    __syncthreads();
    write_AW(smem, smem + 16384, ra, rw, tid);
    if (ii < 15)
      stage_AW(ra2, rw2, hin, RNN, rowA0, a.whh1, RNN, rowW0, (ii + 1) * 128, tid);
    __syncthreads();
    compute_iter(smem, smem + 16384, acc, acc2, lane, wid, 1);
#pragma unroll
    for (int q = 0; q < 4; ++q) ra[q] = ra2[q];
#pragma unroll
    for (int q = 0; q < 6; ++q) rw[q] = rw2[q];
  }
  reduce_gate(acc, acc2, smem, tid, bm, bn, a.ebi, a.ebh, hfold, hfnew, hbnew);
}

// ---- latent + fc1 (one block per batch element) -------------------------
__global__ __launch_bounds__(256) void k_latent(Args a) {
  const int b = blockIdx.x, t = threadIdx.x;
  const float* h = a.hf + (size_t)B_ * RNN + (size_t)b * RNN;  // enc final = slot 1
  __shared__ float sml[128];
  __shared__ float sx[144];
  if (t < 128) {
    const float* w = (t < NZ) ? a.mu_w + (size_t)t * RNN : a.sg_w + (size_t)(t - NZ) * RNN;
    float s0 = 0, s1 = 0, s2 = 0, s3 = 0;
    for (int k = 0; k < RNN; k += 4) {
      s0 += h[k] * w[k];     s1 += h[k + 1] * w[k + 1];
      s2 += h[k + 2] * w[k + 2]; s3 += h[k + 3] * w[k + 3];
    }
    float s = (s0 + s1) + (s2 + s3);
    s += (t < NZ) ? a.mu_b[t] : a.sg_b[t - NZ];
    sml[t] = s;
    if (t < NZ) a.out_mu[b * NZ + t] = s;
    else        a.out_lv[b * NZ + (t - NZ)] = s;
  }
  if (t < 128) {  // init decoder inp (both slots)
    float v = (t < INDIM) ? a.dec[(size_t)b * TD * INDIM + t] : 0.f;
    u16 vb = f2b(v);
    a.inpbf[(size_t)b * 128 + t] = vb;
    a.inpbf[(size_t)B_ * 128 + b * 128 + t] = vb;
    if (t < INDIM) {
      a.inp[b * INDIM + t] = v;
      a.inp[B_ * INDIM + b * INDIM + t] = v;
    }
  }
  __syncthreads();
  if (t < 144) {
    float v = 0.f;
    if (t < NZ) v = sml[t] + a.eps[b * NZ + t] * __expf(0.5f * sml[NZ + t]);
    else if (t < NZ + INDIM) v = a.dec[(size_t)b * TD * INDIM + (t - NZ)];
    sx[t] = v;
  }
  __syncthreads();
  // fc1 -> h slot 0
  for (int j = 0; j < 8; ++j) {
    int n = t + 256 * j;
    const float* w = a.fc1_w + (size_t)n * (NZ + INDIM);
    float s0 = 0, s1 = 0, s2 = 0, s3 = 0;
    int k = 0;
    for (; k + 3 < NZ + INDIM; k += 4) {
      s0 += sx[k] * w[k];     s1 += sx[k + 1] * w[k + 1];
      s2 += sx[k + 2] * w[k + 2]; s3 += sx[k + 3] * w[k + 3];
    }
    float s = (s0 + s1) + (s2 + s3);
    for (; k < NZ + INDIM; ++k) s += sx[k] * w[k];
    s += a.fc1_b[n];
    a.hf[(size_t)b * RNN + n] = s;
    a.hbf[(size_t)b * RNN + n] = f2b(s);
  }
}

// ---- decoder step -------------------------------------------------------
__global__ __launch_bounds__(256, 1) void k_dec(Args a, int t) {
  __shared__ char smem[40960];
  const int tid = threadIdx.x, lane = tid & 63, wid = tid >> 6;
  const int bm = blockIdx.x >> 6, bn = blockIdx.x & 63;
  const int rowA0 = bm * 64, rowW0 = bn * 96;
  const int pin = t & 1, pout = pin ^ 1;
  const int irs = (t - 1) & 1, iws = t & 1;
  const u16* hin = a.hbf + (size_t)pin * B_ * RNN;
  const float* hfold = a.hf + (size_t)pin * B_ * RNN;
  float* hfnew = a.hf + (size_t)pout * B_ * RNN;
  u16* hbnew = a.hbf + (size_t)pout * B_ * RNN;
  const int gtid = blockIdx.x * 256 + tid;

  // epilogue: out_{t-1} = inp_{t-1} + f_{t-1} + fc2_b ; inp_t
  if (t >= 1 && gtid < B_ * INDIM) {
    int b = gtid / INDIM, o = gtid % INDIM;
    float v = a.inp[(size_t)irs * B_ * INDIM + gtid] +
              a.fbuf[(size_t)((t - 1) % 3) * B_ * 96 + b * 96 + o] + a.fc2_b[o];
    a.out[((size_t)b * TD + (t - 1)) * INDIM + o] = v;
    a.inp[(size_t)iws * B_ * INDIM + gtid] = v;
    a.inpbf[(size_t)iws * B_ * 128 + b * 128 + o] = f2b(v);
  }
  // zero f slot for step t+1
  for (int i = gtid; i < B_ * 96; i += 65536)
    a.fbuf[(size_t)((t + 1) % 3) * B_ * 96 + i] = 0.f;

  f32x4 acc[4][6], acc2[4][2];
#pragma unroll
  for (int m = 0; m < 4; ++m) {
#pragma unroll
    for (int n = 0; n < 6; ++n) acc[m][n] = (f32x4)(0.f);
    acc2[m][0] = (f32x4)(0.f); acc2[m][1] = (f32x4)(0.f);
  }

  short8_t ra[4], rw[6], ra2[4], rw2[6];
  // gi iter: inp tile (K=128)
  const u16* inpA = a.inpbf + (size_t)irs * B_ * 128;
  stage_AW(ra, rw, inpA, 128, rowA0, a.wih2, 128, rowW0, 0, tid);
  __syncthreads();
  write_AW(smem, smem + 16384, ra, rw, tid);
  short8_t raf[4];
  if (t >= 1) {   // stage f_{t-1} tile (fp32->bf16), reuses same W
    const float* F = a.fbuf + (size_t)((t - 1) % 3) * B_ * 96;
#pragma unroll
    for (int p = 0; p < 4; ++p) {
      int s = tid + p * 256, r = s >> 4, c = s & 15;
      short8_t v;
#pragma unroll
      for (int e = 0; e < 8; ++e) {
        int o = c * 8 + e;
        float fv = (o < 96) ? F[(bm * 64 + r) * 96 + o] : 0.f;
        v[e] = (short)f2b(fv);
      }
      raf[p] = v;
    }
  }
  __syncthreads();
  compute_iter(smem, smem + 16384, acc, acc2, lane, wid, 0);
  if (t >= 1) {   // gi iter: f tile, same W already in LDS
    __syncthreads();
    write_A(smem, raf, tid);
    __syncthreads();
    compute_iter(smem, smem + 16384, acc, acc2, lane, wid, 0);
  }
  // gh loop (K=2048)
  stage_AW(ra, rw, hin, RNN, rowA0, a.whh2, RNN, rowW0, 0, tid);
  for (int ii = 0; ii < 16; ++ii) {
    __syncthreads();
    write_AW(smem, smem + 16384, ra, rw, tid);
    if (ii < 15)
      stage_AW(ra2, rw2, hin, RNN, rowA0, a.whh2, RNN, rowW0, (ii + 1) * 128, tid);
    __syncthreads();
    compute_iter(smem, smem + 16384, acc, acc2, lane, wid, 1);
#pragma unroll
    for (int q = 0; q < 4; ++q) ra[q] = ra2[q];
#pragma unroll
    for (int q = 0; q < 6; ++q) rw[q] = rw2[q];
  }
  reduce_gate(acc, acc2, smem, tid, bm, bn, (t >= 1) ? a.dbi1 : a.dbi0, a.dbh,
              hfold, hfnew, hbnew);
  // f_t partial from own h' region -> fbuf[t%3]
  fc2_mini(a, hbnew, a.fbuf + (size_t)(t % 3) * B_ * 96, bm, bn, tid, smem);
}

// ---- tail: out_24 --------------------------------------------------------
__global__ void k_tail(Args a) {
  int i = blockIdx.x * blockDim.x + threadIdx.x;
  if (i < B_ * INDIM) {
    int b = i / INDIM, o = i % INDIM;
    float v = a.inp[(size_t)(24 & 1) * B_ * INDIM + i] +
              a.fbuf[(size_t)(24 % 3) * B_ * 96 + b * 96 + o] + a.fc2_b[o];
    a.out[((size_t)b * TD + 24) * INDIM + o] = v;
  }
}

// ===========================================================================
extern "C" void kernel_launch(void* const* d_in, const int* in_sizes, int n_in,
                              void* d_out, int out_size, void* d_ws, size_t ws_size,
                              hipStream_t stream)
{
  const float* enc    = (const float*)d_in[0];
  const float* dec    = (const float*)d_in[1];
  const float* eps    = (const float*)d_in[2];
  const float* fc0_w  = (const float*)d_in[3];
  const float* fc0_b  = (const float*)d_in[4];
  const float* fc1_w  = (const float*)d_in[5];
  const float* fc1_b  = (const float*)d_in[6];
  const float* fc2_w  = (const float*)d_in[7];
  const float* fc2_b  = (const float*)d_in[8];
  const float* mu_w   = (const float*)d_in[9];
  const float* mu_b   = (const float*)d_in[10];
  const float* sg_w   = (const float*)d_in[11];
  const float* sg_b   = (const float*)d_in[12];
  const float* c1_wih = (const float*)d_in[13];
  const float* c1_whh = (const float*)d_in[14];
  const float* c1_bih = (const float*)d_in[15];
  const float* c1_bhh = (const float*)d_in[16];
  const float* c2_wih = (const float*)d_in[17];
  const float* c2_whh = (const float*)d_in[18];
  const float* c2_bih = (const float*)d_in[19];
  const float* c2_bhh = (const float*)d_in[20];

  float* out_outputs = (float*)d_out;
  float* out_mu = out_outputs + (size_t)B_ * TD * INDIM;
  float* out_lv = out_mu + (size_t)B_ * NZ;

  char* ws = (char*)d_ws;
  size_t off = 0;
  auto alloc = [&](size_t bytes) -> void* {
    void* p = ws + off; off += (bytes + 255) & ~(size_t)255; return p;
  };

  u16* whh1_r = (u16*)alloc((size_t)G3 * RNN * 2);
  u16* whh2_r = (u16*)alloc((size_t)G3 * RNN * 2);
  u16* wih1_r = (u16*)alloc((size_t)G3 * RNN * 2);
  u16* wih2_r = (u16*)alloc((size_t)G3 * 128 * 2);
  u16* fc0T   = (u16*)alloc((size_t)256 * RNN * 2);
  u16* fc2T   = (u16*)alloc((size_t)96 * RNN * 2);
  u16* Wenc   = (u16*)alloc((size_t)G3 * 256 * 2);
  u16* pairs  = (u16*)alloc((size_t)SE * B_ * 256 * 2);
  float* hf   = (float*)alloc((size_t)2 * B_ * RNN * 4);
  u16* hbf    = (u16*)alloc((size_t)2 * B_ * RNN * 2);
  float* fbuf = (float*)alloc((size_t)3 * B_ * 96 * 4);
  float* inp  = (float*)alloc((size_t)2 * B_ * INDIM * 4);
  u16* inpbf  = (u16*)alloc((size_t)2 * B_ * 128 * 2);
  float* ebi  = (float*)alloc((size_t)G3 * 4);
  float* ebh  = (float*)alloc((size_t)G3 * 4);
  float* dbi0 = (float*)alloc((size_t)G3 * 4);
  float* dbi1 = (float*)alloc((size_t)G3 * 4);
  float* dbh  = (float*)alloc((size_t)G3 * 4);
  (void)ws_size; (void)in_sizes; (void)n_in; (void)out_size;

  // ---- prep ----
  k_reorder<<<4096, 256, 0, stream>>>(c1_whh, whh1_r, RNN, RNN);
  k_reorder<<<4096, 256, 0, stream>>>(c2_whh, whh2_r, RNN, RNN);
  k_reorder<<<4096, 256, 0, stream>>>(c1_wih, wih1_r, RNN, RNN);
  k_reorder<<<1024, 256, 0, stream>>>(c2_wih, wih2_r, INDIM, 128);
  k_fc0T<<<512, 256, 0, stream>>>(fc0_w, fc0T);
  k_fc2T<<<256, 256, 0, stream>>>(fc2_w, fc2T);
  k_pairs<<<2048, 256, 0, stream>>>(enc, dec, pairs);
  k_bias<<<G3, 256, 0, stream>>>(c1_wih, fc0_b, c1_bih, c1_bhh,
                                 c2_wih, fc2_b, c2_bih, c2_bhh,
                                 ebi, ebh, dbi0, dbi1, dbh);
  k_init<<<2048, 256, 0, stream>>>(hf, hbf, fbuf);
  gemm_bt<<<(G3 / 128) * (256 / 128), 256, 0, stream>>>(wih1_r, fc0T, Wenc, 256, RNN);

  Args a;
  a.pairs = pairs; a.Wenc = Wenc; a.whh1 = whh1_r; a.whh2 = whh2_r;
  a.wih2 = wih2_r; a.fc2T = fc2T;
  a.ebi = ebi; a.ebh = ebh; a.dbi0 = dbi0; a.dbi1 = dbi1; a.dbh = dbh;
  a.eps = eps; a.dec = dec; a.mu_w = mu_w; a.mu_b = mu_b;
  a.sg_w = sg_w; a.sg_b = sg_b; a.fc1_w = fc1_w; a.fc1_b = fc1_b;
  a.fc2_b = fc2_b;
  a.hf = hf; a.hbf = hbf; a.fbuf = fbuf; a.inp = inp; a.inpbf = inpbf;
  a.out = out_outputs; a.out_mu = out_mu; a.out_lv = out_lv;

  for (int t = 0; t < SE; ++t)
    k_enc<<<256, 256, 0, stream>>>(a, t);
  k_latent<<<B_, 256, 0, stream>>>(a);
  for (int t = 0; t < TD; ++t)
    k_dec<<<256, 256, 0, stream>>>(a, t);
  k_tail<<<69, 256, 0, stream>>>(a);
}

// Round 4
// 1736.785 us; speedup vs baseline: 4.0598x; 1.3067x over previous
//
#include <hip/hip_runtime.h>
#include <stdint.h>

#define B_    256
#define SE    49
#define TD    25
#define INDIM 69
#define RNN   2048
#define NZ    64
#define G3    6144

typedef __attribute__((ext_vector_type(8))) short short8_t;
typedef __attribute__((ext_vector_type(4))) float f32x4;
typedef unsigned short u16;

__device__ __forceinline__ float b2f(u16 u) {
  union { unsigned u; float f; } c; c.u = ((unsigned)u) << 16; return c.f;
}
__device__ __forceinline__ u16 f2b(float f) {
  union { float f; unsigned u; } c; c.f = f;
  unsigned u = c.u;
  return (u16)((u + 0x7FFFu + ((u >> 16) & 1u)) >> 16);
}
__device__ __forceinline__ float sigm(float x) { return 1.f / (1.f + __expf(-x)); }

// reordered row R -> original row of [3*RNN];  R = bn*96 + nw*48 + gate*16 + jj
// (gate-triple grouping: each 48-row group holds r/z/n for 16 consecutive j)
__device__ __forceinline__ int rmap(int R) {
  int bn = R / 96, rem = R % 96;
  int nw = rem / 48, g = (rem % 48) / 16, jj = rem % 16;
  return g * RNN + bn * 32 + nw * 16 + jj;
}

// ===========================================================================
// prep kernels
// ===========================================================================
__global__ void k_reorder(const float* __restrict__ src, u16* __restrict__ dst, int K, int Kp) {
  int total = G3 * Kp;
  for (int i = blockIdx.x * blockDim.x + threadIdx.x; i < total; i += gridDim.x * blockDim.x) {
    int R = i / Kp, c = i % Kp;
    dst[i] = (c < K) ? f2b(src[(size_t)rmap(R) * K + c]) : (u16)0;
  }
}

__global__ void k_fc0T(const float* __restrict__ fc0w, u16* __restrict__ dst) {
  int total = 256 * RNN;
  for (int i = blockIdx.x * blockDim.x + threadIdx.x; i < total; i += gridDim.x * blockDim.x) {
    int r = i >> 11, k = i & (RNN - 1);
    dst[i] = (r < 2 * INDIM) ? f2b(fc0w[(size_t)k * (2 * INDIM) + r]) : (u16)0;
  }
}

__global__ void k_fc2T(const float* __restrict__ fc2w, u16* __restrict__ dst) {
  int total = 96 * RNN;
  for (int i = blockIdx.x * blockDim.x + threadIdx.x; i < total; i += gridDim.x * blockDim.x) {
    int r = i >> 11, k = i & (RNN - 1);
    dst[i] = (r < INDIM) ? f2b(fc2w[(size_t)r * RNN + k]) : (u16)0;
  }
}

__global__ void k_pairs(const float* __restrict__ enc, const float* __restrict__ dec,
                        u16* __restrict__ pairs) {
  int total = SE * B_ * 256;
  for (int i = blockIdx.x * blockDim.x + threadIdx.x; i < total; i += gridDim.x * blockDim.x) {
    int c = i & 255, rb = i >> 8;
    int b = rb & 255, t = rb >> 8;
    float v = 0.f;
    if (c < INDIM) v = enc[((size_t)b * SE + t) * INDIM + c];
    else if (c < 2 * INDIM) {
      int cc = c - INDIM;
      v = (t < SE - 1) ? enc[((size_t)b * SE + t + 1) * INDIM + cc]
                       : dec[(size_t)b * TD * INDIM + cc];
    }
    pairs[i] = f2b(v);
  }
}

// mswT[2048][128]: [k][n] where n<64 -> mu_w[n][k], else sg_w[n-64][k]
__global__ void k_msT(const float* __restrict__ muw, const float* __restrict__ sgw,
                      float* __restrict__ dst) {
  int total = RNN * 128;
  for (int i = blockIdx.x * blockDim.x + threadIdx.x; i < total; i += gridDim.x * blockDim.x) {
    int k = i >> 7, n = i & 127;
    dst[i] = (n < NZ) ? muw[(size_t)n * RNN + k] : sgw[(size_t)(n - NZ) * RNN + k];
  }
}

// fc1T[133][2048]: [k][n] = fc1_w[n][k]
__global__ void k_fc1T(const float* __restrict__ w, float* __restrict__ dst) {
  int total = (NZ + INDIM) * RNN;
  for (int i = blockIdx.x * blockDim.x + threadIdx.x; i < total; i += gridDim.x * blockDim.x) {
    int k = i >> 11, n = i & (RNN - 1);
    dst[i] = w[(size_t)n * (NZ + INDIM) + k];
  }
}

__global__ void k_bias(const float* __restrict__ c1wih, const float* __restrict__ fc0b,
                       const float* __restrict__ c1bih, const float* __restrict__ c1bhh,
                       const float* __restrict__ c2wih, const float* __restrict__ fc2b,
                       const float* __restrict__ c2bih, const float* __restrict__ c2bhh,
                       float* __restrict__ ebi, float* __restrict__ ebh,
                       float* __restrict__ dbi0, float* __restrict__ dbi1, float* __restrict__ dbh) {
  int R = blockIdx.x;
  int orig = rmap(R);
  float s = 0.f;
  for (int k = threadIdx.x; k < RNN; k += 256) s += c1wih[(size_t)orig * RNN + k] * fc0b[k];
  __shared__ float red[256];
  red[threadIdx.x] = s; __syncthreads();
  for (int st = 128; st > 0; st >>= 1) {
    if (threadIdx.x < st) red[threadIdx.x] += red[threadIdx.x + st];
    __syncthreads();
  }
  if (threadIdx.x == 0) {
    float k3 = 0.f;
    for (int o = 0; o < INDIM; ++o) k3 += c2wih[(size_t)orig * INDIM + o] * fc2b[o];
    ebi[R] = red[0] + c1bih[orig];
    ebh[R] = c1bhh[orig];
    float d0 = c2bih[orig];
    dbi0[R] = d0;
    dbi1[R] = d0 + k3;
    dbh[R] = c2bhh[orig];
  }
}

// zero h slot0, fbuf[3], out_mu, out_lv
__global__ void k_init(float* __restrict__ hf, u16* __restrict__ hbf, float* __restrict__ fbuf,
                       float* __restrict__ omu, float* __restrict__ olv) {
  int i = blockIdx.x * blockDim.x + threadIdx.x;
  if (i < B_ * RNN) { hf[i] = 0.f; hbf[i] = 0; }
  if (i < 3 * B_ * 96) fbuf[i] = 0.f;
  if (i < B_ * NZ) { omu[i] = 0.f; olv[i] = 0.f; }
}

// ---------------------------------------------------------------------------
// bulk GEMM (r1-proven): C[M,N] = A[M,K]bf16 @ W[N,K]bf16^T ; Wenc build only
// ---------------------------------------------------------------------------
__global__ __launch_bounds__(256) void gemm_bt(
    const u16* __restrict__ A, const u16* __restrict__ W,
    u16* __restrict__ Cb, int N, int K)
{
  constexpr int BM = 128, BN = 128, BK = 64, LDK = BK + 8;
  __shared__ u16 sA[BM * LDK];
  __shared__ u16 sW[BN * LDK];
  const int ntn = N / BN;
  const int bm = blockIdx.x / ntn, bn = blockIdx.x % ntn;
  const int tid = threadIdx.x, lane = tid & 63, wave = tid >> 6;
  const int wr = wave >> 1, wc = wave & 1;
  f32x4 acc[4][4];
#pragma unroll
  for (int i = 0; i < 4; ++i)
#pragma unroll
    for (int j = 0; j < 4; ++j) acc[i][j] = (f32x4)(0.f);
  const int frow = lane & 15, fkq = (lane >> 4) * 8;
  for (int k0 = 0; k0 < K; k0 += BK) {
#pragma unroll
    for (int p = 0; p < 4; ++p) {
      int e = (p * 256 + tid) * 8, r = e / BK, c = e % BK;
      *(short8_t*)&sA[r * LDK + c] = *(const short8_t*)&A[(size_t)(bm * BM + r) * K + k0 + c];
    }
#pragma unroll
    for (int p = 0; p < 4; ++p) {
      int e = (p * 256 + tid) * 8, r = e / BK, c = e % BK;
      *(short8_t*)&sW[r * LDK + c] = *(const short8_t*)&W[(size_t)(bn * BN + r) * K + k0 + c];
    }
    __syncthreads();
#pragma unroll
    for (int kk = 0; kk < BK; kk += 32) {
      short8_t fa[4], fb[4];
#pragma unroll
      for (int m = 0; m < 4; ++m) fa[m] = *(const short8_t*)&sA[(wr * 64 + m * 16 + frow) * LDK + kk + fkq];
#pragma unroll
      for (int n = 0; n < 4; ++n) fb[n] = *(const short8_t*)&sW[(wc * 64 + n * 16 + frow) * LDK + kk + fkq];
#pragma unroll
      for (int m = 0; m < 4; ++m)
#pragma unroll
        for (int n = 0; n < 4; ++n)
          acc[m][n] = __builtin_amdgcn_mfma_f32_16x16x32_bf16(fa[m], fb[n], acc[m][n], 0, 0, 0);
    }
    __syncthreads();
  }
  const int crow = (lane >> 4) * 4, ccol = lane & 15;
#pragma unroll
  for (int n = 0; n < 4; ++n) {
    int col = bn * BN + wc * 64 + n * 16 + ccol;
#pragma unroll
    for (int m = 0; m < 4; ++m)
#pragma unroll
      for (int r = 0; r < 4; ++r) {
        int rowi = bm * BM + wr * 64 + m * 16 + crow + r;
        Cb[(size_t)rowi * N + col] = f2b(acc[m][n][r]);
      }
  }
}

// ===========================================================================
// step kernels: grid 256 = (bm 4) x (bn 64), block 512 = 8 waves (kg4 x nw2)
// LDS: sA[64][512B] @0 (32K), sW[96][512B] @32768 (48K); reduce reuses @0
// swizzle: 16B-slot phys = logical ^ ((row&7)<<2)   [2-way max = free]
// ===========================================================================
struct Args {
  const u16 *pairs, *Wenc, *whh1, *whh2, *wih2, *fc2T;
  const float *ebi, *ebh, *dbi0, *dbi1, *dbh;
  const float *eps, *dec, *fc1_b, *fc2_b;
  const float *mswT, *fc1T, *mu_b, *sg_b;
  float* hf;    // [2][256][2048]
  u16*   hbf;   // [2][256][2048]
  float* fbuf;  // [3][256][96]
  float* inp;   // [2][256][69]
  u16*   inpbf; // [2][256][128]
  float* fc1x;  // [256][144]
  float *out, *out_mu, *out_lv;
};

__device__ __forceinline__ void stage_gh(short8_t (&ra)[4], short8_t (&rw)[6],
    const u16* __restrict__ A, const u16* __restrict__ W,
    int rowA0, int rowW0, int k0, int tid) {
#pragma unroll
  for (int p = 0; p < 4; ++p) {
    int s = tid + p * 512, r = s >> 5, c = s & 31;
    ra[p] = *(const short8_t*)&A[(size_t)(rowA0 + r) * RNN + k0 + c * 8];
  }
#pragma unroll
  for (int p = 0; p < 6; ++p) {
    int s = tid + p * 512, r = s >> 5, c = s & 31;
    rw[p] = *(const short8_t*)&W[(size_t)(rowW0 + r) * RNN + k0 + c * 8];
  }
}

__device__ __forceinline__ void write_AW(char* sA, char* sW,
    short8_t (&ra)[4], short8_t (&rw)[6], int tid) {
#pragma unroll
  for (int p = 0; p < 4; ++p) {
    int s = tid + p * 512, r = s >> 5, c = s & 31;
    *(short8_t*)&sA[r * 512 + ((c ^ ((r & 7) << 2)) * 16)] = ra[p];
  }
#pragma unroll
  for (int p = 0; p < 6; ++p) {
    int s = tid + p * 512, r = s >> 5, c = s & 31;
    *(short8_t*)&sW[r * 512 + ((c ^ ((r & 7) << 2)) * 16)] = rw[p];
  }
}

__device__ __forceinline__ void compute2(const char* sA, const char* sW,
    f32x4 (&aR)[4], f32x4 (&aZ)[4], f32x4 (&aN)[4], int kg, int nw, int lane) {
#pragma unroll
  for (int s = 0; s < 2; ++s) {
    const int L = kg * 8 + s * 4 + (lane >> 4);
    short8_t fa[4], fbv[3];
#pragma unroll
    for (int m = 0; m < 4; ++m) {
      int r = m * 16 + (lane & 15);
      fa[m] = *(const short8_t*)&sA[r * 512 + ((L ^ ((r & 7) << 2)) * 16)];
    }
#pragma unroll
    for (int g = 0; g < 3; ++g) {
      int r = nw * 48 + g * 16 + (lane & 15);
      fbv[g] = *(const short8_t*)&sW[r * 512 + ((L ^ ((r & 7) << 2)) * 16)];
    }
#pragma unroll
    for (int m = 0; m < 4; ++m) {
      aR[m] = __builtin_amdgcn_mfma_f32_16x16x32_bf16(fa[m], fbv[0], aR[m], 0, 0, 0);
      aZ[m] = __builtin_amdgcn_mfma_f32_16x16x32_bf16(fa[m], fbv[1], aZ[m], 0, 0, 0);
      aN[m] = __builtin_amdgcn_mfma_f32_16x16x32_bf16(fa[m], fbv[2], aN[m], 0, 0, 0);
    }
  }
}

// chunk-major k-reduce (3 barriers) + in-register GRU gate on waves 0,1
__device__ __forceinline__ void reduce_and_gate(
    f32x4 (&aR)[4], f32x4 (&aZ)[4], f32x4 (&aNI)[4], f32x4 (&aNH)[4],
    char* smem, int tid, int bm, int bn,
    const float* __restrict__ bi, const float* __restrict__ bh,
    const float* __restrict__ hfold, float* __restrict__ hfnew, u16* __restrict__ hbnew) {
  const int lane = tid & 63, wid = tid >> 6;
  auto wr16 = [&](int slots, int w) {
#pragma unroll
    for (int m = 0; m < 4; ++m) {
      *(f32x4*)&smem[(((0 * 4 + m) * slots + w) * 64 + lane) * 16] = aR[m];
      *(f32x4*)&smem[(((1 * 4 + m) * slots + w) * 64 + lane) * 16] = aZ[m];
      *(f32x4*)&smem[(((2 * 4 + m) * slots + w) * 64 + lane) * 16] = aNI[m];
      *(f32x4*)&smem[(((3 * 4 + m) * slots + w) * 64 + lane) * 16] = aNH[m];
    }
  };
  auto add16 = [&](int slots, int w) {
#pragma unroll
    for (int m = 0; m < 4; ++m) {
      aR[m]  += *(const f32x4*)&smem[(((0 * 4 + m) * slots + w) * 64 + lane) * 16];
      aZ[m]  += *(const f32x4*)&smem[(((1 * 4 + m) * slots + w) * 64 + lane) * 16];
      aNI[m] += *(const f32x4*)&smem[(((2 * 4 + m) * slots + w) * 64 + lane) * 16];
      aNH[m] += *(const f32x4*)&smem[(((3 * 4 + m) * slots + w) * 64 + lane) * 16];
    }
  };
  __syncthreads();
  if (wid >= 4) wr16(4, wid - 4);          // kg 2,3 write (64 KB)
  __syncthreads();
  if (wid < 4) add16(4, wid);              // kg 0,1 add
  __syncthreads();
  if (wid == 2 || wid == 3) wr16(2, wid - 2);  // kg1 write (32 KB)
  __syncthreads();
  if (wid < 2) {
    add16(2, wid);
    const int nw = wid, jj = lane & 15;
    const int Rb = bn * 96 + nw * 48;
    const float biR = bi[Rb + jj],      bhR = bh[Rb + jj];
    const float biZ = bi[Rb + 16 + jj], bhZ = bh[Rb + 16 + jj];
    const float biN = bi[Rb + 32 + jj], bhN = bh[Rb + 32 + jj];
    const int j = bn * 32 + nw * 16 + jj;
#pragma unroll
    for (int m = 0; m < 4; ++m)
#pragma unroll
      for (int q = 0; q < 4; ++q) {
        int b = bm * 64 + m * 16 + ((lane >> 4) << 2) + q;
        float r = sigm(aR[m][q] + biR + bhR);
        float z = sigm(aZ[m][q] + biZ + bhZ);
        float nn = 2.f * sigm(2.f * ((aNI[m][q] + biN) + r * (aNH[m][q] + bhN))) - 1.f;
        float hv = (1.f - z) * nn + z * hfold[(size_t)b * RNN + j];
        hfnew[(size_t)b * RNN + j] = hv;
        hbnew[(size_t)b * RNN + j] = f2b(hv);
      }
  }
}

// ---- encoder step ---------------------------------------------------------
__global__ __launch_bounds__(512, 1) void k_enc(Args a, int t) {
  __shared__ char smem[81920];
  char* sA = smem;
  char* sW = smem + 32768;
  const int tid = threadIdx.x, lane = tid & 63, wid = tid >> 6;
  const int kg = wid >> 1, nw = wid & 1;
  const int bm = blockIdx.x >> 6, bn = blockIdx.x & 63;
  const int rowA0 = bm * 64, rowW0 = bn * 96;
  const int pin = t & 1, pout = pin ^ 1;
  const u16* hin = a.hbf + (size_t)pin * B_ * RNN;
  const float* hfold = a.hf + (size_t)pin * B_ * RNN;
  float* hfnew = a.hf + (size_t)pout * B_ * RNN;
  u16* hbnew = a.hbf + (size_t)pout * B_ * RNN;

  f32x4 aR[4], aZ[4], aNI[4], aNH[4];
#pragma unroll
  for (int m = 0; m < 4; ++m) {
    aR[m] = (f32x4)(0.f); aZ[m] = (f32x4)(0.f);
    aNI[m] = (f32x4)(0.f); aNH[m] = (f32x4)(0.f);
  }

  short8_t ra[4], rw[6], ra2[4], rw2[6];
  // iter 0 = gi: pairs[t] (64x256) @ Wenc (96x256)
  const u16* P = a.pairs + (size_t)t * B_ * 256;
#pragma unroll
  for (int p = 0; p < 4; ++p) {
    int s = tid + p * 512, r = s >> 5, c = s & 31;
    ra[p] = *(const short8_t*)&P[(size_t)(rowA0 + r) * 256 + c * 8];
  }
#pragma unroll
  for (int p = 0; p < 6; ++p) {
    int s = tid + p * 512, r = s >> 5, c = s & 31;
    rw[p] = *(const short8_t*)&a.Wenc[(size_t)(rowW0 + r) * 256 + c * 8];
  }
  write_AW(sA, sW, ra, rw, tid);
  stage_gh(ra2, rw2, hin, a.whh1, rowA0, rowW0, 0, tid);
  __syncthreads();
  compute2(sA, sW, aR, aZ, aNI, kg, nw, lane);
  // iters 1..8 = gh (K=2048)
  for (int i = 1; i <= 8; ++i) {
#pragma unroll
    for (int q = 0; q < 4; ++q) ra[q] = ra2[q];
#pragma unroll
    for (int q = 0; q < 6; ++q) rw[q] = rw2[q];
    __syncthreads();
    write_AW(sA, sW, ra, rw, tid);
    if (i < 8) stage_gh(ra2, rw2, hin, a.whh1, rowA0, rowW0, i * 256, tid);
    __syncthreads();
    compute2(sA, sW, aR, aZ, aNH, kg, nw, lane);
  }
  reduce_and_gate(aR, aZ, aNI, aNH, smem, tid, bm, bn, a.ebi, a.ebh, hfold, hfnew, hbnew);
}

// ---- decoder step ---------------------------------------------------------
__global__ __launch_bounds__(512, 1) void k_dec(Args a, int t) {
  __shared__ char smem[81920];
  char* sA = smem;
  char* sW = smem + 32768;
  const int tid = threadIdx.x, lane = tid & 63, wid = tid >> 6;
  const int kg = wid >> 1, nw = wid & 1;
  const int bm = blockIdx.x >> 6, bn = blockIdx.x & 63;
  const int rowA0 = bm * 64, rowW0 = bn * 96;
  const int pin = t & 1, pout = pin ^ 1;
  const int irs = (t + 1) & 1, iws = t & 1;
  const int frd = (t + 2) % 3;       // f_{t-1} slot
  const u16* hin = a.hbf + (size_t)pin * B_ * RNN;
  const float* hfold = a.hf + (size_t)pin * B_ * RNN;
  float* hfnew = a.hf + (size_t)pout * B_ * RNN;
  u16* hbnew = a.hbf + (size_t)pout * B_ * RNN;
  const int gtid = blockIdx.x * 512 + tid;

  // epilogue: out_{t-1} = inp_{t-1} + f_{t-1} + fc2_b ; write inp_t
  if (t >= 1 && gtid < B_ * INDIM) {
    int b = gtid / INDIM, o = gtid % INDIM;
    float v = a.inp[(size_t)irs * B_ * INDIM + gtid] +
              a.fbuf[(size_t)frd * B_ * 96 + b * 96 + o] + a.fc2_b[o];
    a.out[((size_t)b * TD + (t - 1)) * INDIM + o] = v;
    a.inp[(size_t)iws * B_ * INDIM + gtid] = v;
    a.inpbf[(size_t)iws * B_ * 128 + b * 128 + o] = f2b(v);
  }
  // zero f slot for step t+1
  if (gtid < B_ * 96)
    a.fbuf[(size_t)((t + 1) % 3) * B_ * 96 + gtid] = 0.f;

  f32x4 aR[4], aZ[4], aNI[4], aNH[4];
#pragma unroll
  for (int m = 0; m < 4; ++m) {
    aR[m] = (f32x4)(0.f); aZ[m] = (f32x4)(0.f);
    aNI[m] = (f32x4)(0.f); aNH[m] = (f32x4)(0.f);
  }

  short8_t ra[4], rw[6], ra2[4], rw2[6];
  // iter 0 = gi: A = [inpbf(k 0..127) | f_{t-1} bf16 (k 128..255)], W = [wih2 | wih2]
  const u16* inpA = a.inpbf + (size_t)irs * B_ * 128;
  const float* F = a.fbuf + (size_t)frd * B_ * 96;
#pragma unroll
  for (int p = 0; p < 4; ++p) {
    int s = tid + p * 512, r = s >> 5, c = s & 31;
    if (c < 16) {
      ra[p] = *(const short8_t*)&inpA[(size_t)(rowA0 + r) * 128 + c * 8];
    } else {
      short8_t v;
#pragma unroll
      for (int e = 0; e < 8; ++e) {
        int o = (c - 16) * 8 + e;
        float fv = (o < 96) ? F[(size_t)(rowA0 + r) * 96 + o] : 0.f;
        v[e] = (short)f2b(fv);
      }
      ra[p] = v;
    }
  }
#pragma unroll
  for (int p = 0; p < 6; ++p) {
    int s = tid + p * 512, r = s >> 5, c = s & 31;
    rw[p] = *(const short8_t*)&a.wih2[(size_t)(rowW0 + r) * 128 + (c & 15) * 8];
  }
  __syncthreads();   // epilogue writes done before LDS phase (also orders nothing harmful)
  write_AW(sA, sW, ra, rw, tid);
  stage_gh(ra2, rw2, hin, a.whh2, rowA0, rowW0, 0, tid);
  __syncthreads();
  compute2(sA, sW, aR, aZ, aNI, kg, nw, lane);
  for (int i = 1; i <= 8; ++i) {
#pragma unroll
    for (int q = 0; q < 4; ++q) ra[q] = ra2[q];
#pragma unroll
    for (int q = 0; q < 6; ++q) rw[q] = rw2[q];
    __syncthreads();
    write_AW(sA, sW, ra, rw, tid);
    if (i < 8) stage_gh(ra2, rw2, hin, a.whh2, rowA0, rowW0, i * 256, tid);
    __syncthreads();
    compute2(sA, sW, aR, aZ, aNH, kg, nw, lane);
  }
  reduce_and_gate(aR, aZ, aNI, aNH, smem, tid, bm, bn,
                  (t >= 1) ? a.dbi1 : a.dbi0, a.dbh, hfold, hfnew, hbnew);

  // ---- f_t partial: fbuf[t%3][rows bm*64..][96] += h'[rows][k=bn*32..] @ fc2T^T
  __syncthreads();   // h' global writes drained & visible block-wide
  if (tid < 256) {
    int r = tid >> 2, c16 = tid & 3;
    *(short8_t*)&smem[r * 80 + c16 * 16] =
        *(const short8_t*)&hbnew[(size_t)(bm * 64 + r) * RNN + bn * 32 + c16 * 8];
  }
  if (tid < 384) {
    int r = tid >> 2, c16 = tid & 3;
    if (tid < 256) {
      // also load first 256 chunks of fc2T below via second range
    }
    (void)r; (void)c16;
  }
  {
    int s2 = tid;
    if (s2 < 384) {
      int r = s2 >> 2, c16 = s2 & 3;
      *(short8_t*)&smem[5120 + r * 80 + c16 * 16] =
          *(const short8_t*)&a.fc2T[(size_t)r * RNN + bn * 32 + c16 * 8];
    }
  }
  __syncthreads();
  if (wid < 4) {
    const int wr = wid >> 1, wc = wid & 1;
    short8_t fa[2], fb[3];
    f32x4 accf[2][3];
#pragma unroll
    for (int m = 0; m < 2; ++m)
#pragma unroll
      for (int n = 0; n < 3; ++n) accf[m][n] = (f32x4)(0.f);
#pragma unroll
    for (int m = 0; m < 2; ++m) {
      int r = wr * 32 + m * 16 + (lane & 15);
      fa[m] = *(const short8_t*)&smem[r * 80 + ((lane >> 4) << 4)];
    }
#pragma unroll
    for (int n = 0; n < 3; ++n) {
      int r = wc * 48 + n * 16 + (lane & 15);
      fb[n] = *(const short8_t*)&smem[5120 + r * 80 + ((lane >> 4) << 4)];
    }
#pragma unroll
    for (int m = 0; m < 2; ++m)
#pragma unroll
      for (int n = 0; n < 3; ++n)
        accf[m][n] = __builtin_amdgcn_mfma_f32_16x16x32_bf16(fa[m], fb[n], accf[m][n], 0, 0, 0);
    float* fdst = a.fbuf + (size_t)(t % 3) * B_ * 96;
#pragma unroll
    for (int m = 0; m < 2; ++m)
#pragma unroll
      for (int n = 0; n < 3; ++n)
#pragma unroll
        for (int q = 0; q < 4; ++q) {
          int row = bm * 64 + wr * 32 + m * 16 + ((lane >> 4) << 2) + q;
          int col = wc * 48 + n * 16 + (lane & 15);
          atomicAdd(&fdst[row * 96 + col], accf[m][n][q]);
        }
  }
}

// ---- latent: mu/sigma GEMM (b-tiled, k-chunked, fp32, atomic partials) ----
__global__ __launch_bounds__(256) void k_ms(Args a) {
  __shared__ float hs[16 * 128];
  const int bt = blockIdx.x >> 4, kc = blockIdx.x & 15;
  const int tid = threadIdx.x;
  const float* h1 = a.hf + (size_t)B_ * RNN;     // enc final = slot 1
#pragma unroll
  for (int p = 0; p < 8; ++p) {
    int ii = tid + p * 256;
    int bl = ii >> 7, kl = ii & 127;
    hs[ii] = h1[(size_t)(bt * 16 + bl) * RNN + kc * 128 + kl];
  }
  __syncthreads();
  const int n = tid & 127, bg = tid >> 7;
  const float* wp = a.mswT + (size_t)(kc * 128) * 128 + n;
  float ps[8];
#pragma unroll
  for (int i = 0; i < 8; ++i) ps[i] = 0.f;
  for (int k = 0; k < 128; ++k) {
    float wv = wp[(size_t)k * 128];
#pragma unroll
    for (int i = 0; i < 8; ++i) ps[i] += wv * hs[(bg * 8 + i) * 128 + k];
  }
#pragma unroll
  for (int i = 0; i < 8; ++i) {
    int b = bt * 16 + bg * 8 + i;
    if (n < NZ) atomicAdd(&a.out_mu[b * NZ + n], ps[i]);
    else        atomicAdd(&a.out_lv[b * NZ + (n - NZ)], ps[i]);
  }
}

// ---- sample + fc1 input + decoder inp init --------------------------------
__global__ void k_sample(Args a) {
  int gid = blockIdx.x * blockDim.x + threadIdx.x;
  if (gid < B_ * NZ) {
    int b = gid >> 6, n = gid & 63;
    float mu = a.out_mu[gid] + a.mu_b[n];
    float lv = a.out_lv[gid] + a.sg_b[n];
    a.out_mu[gid] = mu;
    a.out_lv[gid] = lv;
    a.fc1x[b * 144 + n] = mu + a.eps[gid] * __expf(0.5f * lv);
  }
  if (gid < B_ * 128) {
    int b = gid >> 7, c = gid & 127;
    float v = (c < INDIM) ? a.dec[(size_t)b * TD * INDIM + c] : 0.f;
    u16 vb = f2b(v);
    a.inpbf[(size_t)b * 128 + c] = vb;
    a.inpbf[(size_t)B_ * 128 + b * 128 + c] = vb;
    if (c < INDIM) {
      a.inp[b * INDIM + c] = v;
      a.inp[B_ * INDIM + b * INDIM + c] = v;
      a.fc1x[b * 144 + NZ + c] = v;
    }
  }
}

// ---- fc1: h0 = fc1x @ fc1T (K=133), b-tiled, coalesced --------------------
__global__ __launch_bounds__(256) void k_fc1(Args a) {
  __shared__ float xs[16 * 144];
  const int bt = blockIdx.x >> 3, nt = blockIdx.x & 7;
  const int tid = threadIdx.x;
#pragma unroll
  for (int p = 0; p < 9; ++p) {
    int ii = tid + p * 256;
    if (ii < 16 * 144) {
      int bl = ii / 144, k = ii % 144;
      xs[ii] = (k < NZ + INDIM) ? a.fc1x[(size_t)(bt * 16 + bl) * 144 + k] : 0.f;
    }
  }
  __syncthreads();
  const int n = nt * 256 + tid;
  float s[16];
#pragma unroll
  for (int i = 0; i < 16; ++i) s[i] = 0.f;
  for (int k = 0; k < NZ + INDIM; ++k) {
    float wv = a.fc1T[(size_t)k * RNN + n];
#pragma unroll
    for (int i = 0; i < 16; ++i) s[i] += wv * xs[i * 144 + k];
  }
  float bv = a.fc1_b[n];
#pragma unroll
  for (int i = 0; i < 16; ++i) {
    int b = bt * 16 + i;
    float v = s[i] + bv;
    a.hf[(size_t)b * RNN + n] = v;          // slot 0
    a.hbf[(size_t)b * RNN + n] = f2b(v);
  }
}

// ---- tail: out_24 ---------------------------------------------------------
__global__ void k_tail(Args a) {
  int i = blockIdx.x * blockDim.x + threadIdx.x;
  if (i < B_ * INDIM) {
    int b = i / INDIM, o = i % INDIM;
    float v = a.inp[(size_t)(24 & 1) * B_ * INDIM + i] +
              a.fbuf[(size_t)(24 % 3) * B_ * 96 + b * 96 + o] + a.fc2_b[o];
    a.out[((size_t)b * TD + 24) * INDIM + o] = v;
  }
}

// ===========================================================================
extern "C" void kernel_launch(void* const* d_in, const int* in_sizes, int n_in,
                              void* d_out, int out_size, void* d_ws, size_t ws_size,
                              hipStream_t stream)
{
  const float* enc    = (const float*)d_in[0];
  const float* dec    = (const float*)d_in[1];
  const float* eps    = (const float*)d_in[2];
  const float* fc0_w  = (const float*)d_in[3];
  const float* fc0_b  = (const float*)d_in[4];
  const float* fc1_w  = (const float*)d_in[5];
  const float* fc1_b  = (const float*)d_in[6];
  const float* fc2_w  = (const float*)d_in[7];
  const float* fc2_b  = (const float*)d_in[8];
  const float* mu_w   = (const float*)d_in[9];
  const float* mu_b   = (const float*)d_in[10];
  const float* sg_w   = (const float*)d_in[11];
  const float* sg_b   = (const float*)d_in[12];
  const float* c1_wih = (const float*)d_in[13];
  const float* c1_whh = (const float*)d_in[14];
  const float* c1_bih = (const float*)d_in[15];
  const float* c1_bhh = (const float*)d_in[16];
  const float* c2_wih = (const float*)d_in[17];
  const float* c2_whh = (const float*)d_in[18];
  const float* c2_bih = (const float*)d_in[19];
  const float* c2_bhh = (const float*)d_in[20];

  float* out_outputs = (float*)d_out;
  float* out_mu = out_outputs + (size_t)B_ * TD * INDIM;
  float* out_lv = out_mu + (size_t)B_ * NZ;

  char* ws = (char*)d_ws;
  size_t off = 0;
  auto alloc = [&](size_t bytes) -> void* {
    void* p = ws + off; off += (bytes + 255) & ~(size_t)255; return p;
  };

  u16* whh1_r = (u16*)alloc((size_t)G3 * RNN * 2);
  u16* whh2_r = (u16*)alloc((size_t)G3 * RNN * 2);
  u16* wih1_r = (u16*)alloc((size_t)G3 * RNN * 2);
  u16* wih2_r = (u16*)alloc((size_t)G3 * 128 * 2);
  u16* fc0T   = (u16*)alloc((size_t)256 * RNN * 2);
  u16* fc2T   = (u16*)alloc((size_t)96 * RNN * 2);
  u16* Wenc   = (u16*)alloc((size_t)G3 * 256 * 2);
  u16* pairs  = (u16*)alloc((size_t)SE * B_ * 256 * 2);
  float* hf   = (float*)alloc((size_t)2 * B_ * RNN * 4);
  u16* hbf    = (u16*)alloc((size_t)2 * B_ * RNN * 2);
  float* fbuf = (float*)alloc((size_t)3 * B_ * 96 * 4);
  float* inp  = (float*)alloc((size_t)2 * B_ * INDIM * 4);
  u16* inpbf  = (u16*)alloc((size_t)2 * B_ * 128 * 2);
  float* fc1x = (float*)alloc((size_t)B_ * 144 * 4);
  float* mswT = (float*)alloc((size_t)RNN * 128 * 4);
  float* fc1T = (float*)alloc((size_t)(NZ + INDIM) * RNN * 4);
  float* ebi  = (float*)alloc((size_t)G3 * 4);
  float* ebh  = (float*)alloc((size_t)G3 * 4);
  float* dbi0 = (float*)alloc((size_t)G3 * 4);
  float* dbi1 = (float*)alloc((size_t)G3 * 4);
  float* dbh  = (float*)alloc((size_t)G3 * 4);
  (void)ws_size; (void)in_sizes; (void)n_in; (void)out_size;

  // ---- prep ----
  k_reorder<<<4096, 256, 0, stream>>>(c1_whh, whh1_r, RNN, RNN);
  k_reorder<<<4096, 256, 0, stream>>>(c2_whh, whh2_r, RNN, RNN);
  k_reorder<<<4096, 256, 0, stream>>>(c1_wih, wih1_r, RNN, RNN);
  k_reorder<<<1024, 256, 0, stream>>>(c2_wih, wih2_r, INDIM, 128);
  k_fc0T<<<512, 256, 0, stream>>>(fc0_w, fc0T);
  k_fc2T<<<256, 256, 0, stream>>>(fc2_w, fc2T);
  k_pairs<<<2048, 256, 0, stream>>>(enc, dec, pairs);
  k_msT<<<256, 256, 0, stream>>>(mu_w, sg_w, mswT);
  k_fc1T<<<256, 256, 0, stream>>>(fc1_w, fc1T);
  k_bias<<<G3, 256, 0, stream>>>(c1_wih, fc0_b, c1_bih, c1_bhh,
                                 c2_wih, fc2_b, c2_bih, c2_bhh,
                                 ebi, ebh, dbi0, dbi1, dbh);

  Args a;
  a.pairs = pairs; a.Wenc = Wenc; a.whh1 = whh1_r; a.whh2 = whh2_r;
  a.wih2 = wih2_r; a.fc2T = fc2T;
  a.ebi = ebi; a.ebh = ebh; a.dbi0 = dbi0; a.dbi1 = dbi1; a.dbh = dbh;
  a.eps = eps; a.dec = dec; a.fc1_b = fc1_b; a.fc2_b = fc2_b;
  a.mswT = mswT; a.fc1T = fc1T; a.mu_b = mu_b; a.sg_b = sg_b;
  a.hf = hf; a.hbf = hbf; a.fbuf = fbuf; a.inp = inp; a.inpbf = inpbf;
  a.fc1x = fc1x; a.out = out_outputs; a.out_mu = out_mu; a.out_lv = out_lv;

  k_init<<<2048, 256, 0, stream>>>(hf, hbf, fbuf, out_mu, out_lv);
  gemm_bt<<<(G3 / 128) * (256 / 128), 256, 0, stream>>>(wih1_r, fc0T, Wenc, 256, RNN);

  for (int t = 0; t < SE; ++t)
    k_enc<<<256, 512, 0, stream>>>(a, t);
  k_ms<<<256, 256, 0, stream>>>(a);
  k_sample<<<128, 256, 0, stream>>>(a);
  k_fc1<<<128, 256, 0, stream>>>(a);
  for (int t = 0; t < TD; ++t)
    k_dec<<<256, 512, 0, stream>>>(a, t);
  k_tail<<<69, 256, 0, stream>>>(a);
}